// Round 1
// baseline (235.801 us; speedup 1.0000x reference)
//
#include <hip/hip_runtime.h>
#include <hip/hip_cooperative_groups.h>

namespace cg = cooperative_groups;

// Problem constants (from reference): B=4,S=2048,K=2,C=32,D=128,P=128
// R8: full fusion of the proven 3-kernel structure (R4, 88.4us) into ONE
// cooperative kernel. Rationale: total algorithmic traffic ~48MB (mostly
// L2/L3-resident) => ~8us roofline vs 88.6us measured; all top-5 rocprof
// rows are harness ws-poison fills => none of our kernels is BW/compute
// bound. Remaining cost is inter-kernel graph gaps + dispatch ramps for
// tiny grids. Phase-1 body is VERBATIM from R4 (R5/R6/R7 showed its
// geometry is load-bearing). Co-residency for grid.sync(): 64KB LDS ->
// <=2 blocks/CU, 256 blocks <= 512 slots. Fallback if cooperative+graph
// capture fails: hipMemsetAsync'd spin barrier.
#define P_  128
#define C_  32
#define D_  128
#define BS_ 8192          // B*S rows
#define PD_ (P_*D_)       // 16384 floats = 64 KB
#define NB_ 256           // privatized partial tables (= grid)

__global__ __launch_bounds__(512) void fused_all(
    const int* __restrict__ idx, const float* __restrict__ keys,
    const float* __restrict__ values, const float* __restrict__ queries,
    float* __restrict__ partials, float* __restrict__ means,
    float* __restrict__ out)
{
    __shared__ float lmeans[PD_];
    float4* lm4 = (float4*)lmeans;
    const int tid = threadIdx.x;

    // ---------------- Phase 1: per-block partial tables (R4-verbatim) ----
    for (int i = tid; i < PD_ / 4; i += 512) lm4[i] = float4{0.f, 0.f, 0.f, 0.f};
    __syncthreads();

    const int lane = tid & 63;
    const int wave = tid >> 6;                 // 0..7
    const int rbase = blockIdx.x * 32 + wave;  // rows: rbase + 8*j

    float kv[4], va[4], vb[4];
    int2  ii[4];
    #pragma unroll
    for (int j = 0; j < 4; ++j) {
        const int r = rbase + 8 * j;
        kv[j] = keys[(size_t)r * 64 + lane];          // [K=2,C=32] flat
        ii[j] = ((const int2*)idx)[r];                // both partition ids
        va[j] = values[(size_t)r * D_ + lane];
        vb[j] = values[(size_t)r * D_ + 64 + lane];
    }

    #pragma unroll
    for (int j = 0; j < 4; ++j) {
        float s = kv[j];
        s += __shfl_xor(s, 16);   // reduce within each 32-lane half
        s += __shfl_xor(s, 8);
        s += __shfl_xor(s, 4);
        s += __shfl_xor(s, 2);
        s += __shfl_xor(s, 1);
        const float ks0 = __shfl(s, 0)  * (1.f / 32.f);  // mean_c keys[r,0,:]
        const float ks1 = __shfl(s, 32) * (1.f / 32.f);  // mean_c keys[r,1,:]
        // stride-1 across lanes -> 2 lanes/bank, conflict-free
        atomicAdd(&lmeans[ii[j].x * D_ + lane],      ks0 * va[j]);
        atomicAdd(&lmeans[ii[j].x * D_ + 64 + lane], ks0 * vb[j]);
        atomicAdd(&lmeans[ii[j].y * D_ + lane],      ks1 * va[j]);
        atomicAdd(&lmeans[ii[j].y * D_ + 64 + lane], ks1 * vb[j]);
    }
    __syncthreads();

    {
        float4* dst = (float4*)(partials + (size_t)blockIdx.x * PD_);
        for (int i = tid; i < PD_ / 4; i += 512) dst[i] = lm4[i];
    }

    __threadfence();          // device-scope release of partials (cross-XCD)
    cg::this_grid().sync();

    // ---------------- Phase 2: means[e] = sum_b partials[b][e] -----------
    // Block owns 64 elements; 8 wave-groups each sum 32 tables; LDS combine.
    const int el = tid & 63;                  // element within block's chunk
    const int g  = tid >> 6;                  // table-group 0..7
    const int e  = blockIdx.x * 64 + el;      // global element 0..16383
    float s2 = 0.f;
    #pragma unroll 8
    for (int j = 0; j < 32; ++j)
        s2 += partials[(size_t)(g * 32 + j) * PD_ + e];
    lmeans[g * 64 + el] = s2;                 // reuse lmeans as red[8][64]
    __syncthreads();
    if (tid < 64) {
        float m = lmeans[tid];
        #pragma unroll
        for (int g2 = 1; g2 < 8; ++g2) m += lmeans[g2 * 64 + tid];
        means[blockIdx.x * 64 + tid] = m;
    }

    __threadfence();          // device-scope release of means (cross-XCD)
    cg::this_grid().sync();

    // ---------------- Phase 3: emit (same rows this block scattered) -----
    // 1024 float4 per block = 2 per thread. 32 consecutive lanes share one
    // row -> means gathers are 512B segments (L2-hot, table is 64KB).
    const float4* m4 = (const float4*)means;
    const float4* q4 = (const float4*)queries;
    float4*       o4 = (float4*)out;
    #pragma unroll
    for (int it = 0; it < 2; ++it) {
        const int gid = blockIdx.x * 1024 + it * 512 + tid;  // [0, 262144)
        const int row = gid >> 5;                            // 32 float4/row
        const int d4  = gid & 31;
        const int2 p  = ((const int2*)idx)[row];
        const float4 q = q4[gid];
        const float4 a = m4[p.x * 32 + d4];
        const float4 b = m4[p.y * 32 + d4];
        float4 o;
        o.x = (a.x + b.x) * q.x;
        o.y = (a.y + b.y) * q.y;
        o.z = (a.z + b.z) * q.z;
        o.w = (a.w + b.w) * q.w;
        o4[gid] = o;
    }
}

extern "C" void kernel_launch(void* const* d_in, const int* in_sizes, int n_in,
                              void* d_out, int out_size, void* d_ws, size_t ws_size,
                              hipStream_t stream) {
    const int*   idx     = (const int*)d_in[0];    // [B,S,K] int32
    const float* keys    = (const float*)d_in[1];  // [B,S,K,C] fp32
    const float* values  = (const float*)d_in[2];  // [B,S,D]  fp32
    const float* queries = (const float*)d_in[3];  // [B,S,D]  fp32
    float* out = (float*)d_out;
    float* ws  = (float*)d_ws;

    // ws layout: [NB_ partial tables of PD_ floats][1 final means table]
    float* partials = ws;
    float* means    = ws + (size_t)NB_ * PD_;

    void* args[] = {(void*)&idx, (void*)&keys, (void*)&values, (void*)&queries,
                    (void*)&partials, (void*)&means, (void*)&out};
    hipLaunchCooperativeKernel((void*)fused_all, dim3(NB_), dim3(512),
                               args, 0, stream);
}

// Round 2
// 88.664 us; speedup vs baseline: 2.6595x; 2.6595x over previous
//
#include <hip/hip_runtime.h>
#include <hip/hip_bf16.h>

// Problem constants (from reference): B=4,S=2048,K=2,C=32,D=128,P=128
// R9: verbatim revert to R4 (best measured: 88.4-88.6 us).
// Validated by failed perturbations:
//   R5 global-atomic fold   (+10us: ~2.4ns/op atomic throughput)
//   R6 sharded atomics      (+8us)
//   R7 64-block/16-deep pf  (+29us: VGPR cap 52 sinks prefetch -> serial)
//   R8 cooperative fusion   (+147us: 2x grid.sync + device fences on
//       256 blocks across 8 XCDs stall ~150us; VALUBusy 0.6%, HBM 2.8%)
// Dur decomposition (R0/R1 rocprof): ~85.6us of dur is harness ws-poison
// (2x 256MiB fillBufferAligned at ~6.3TB/s, inside the timed window);
// the three kernels below total ~3us (traffic L2/L3-resident). We are at
// the measurement floor.
#define P_  128
#define C_  32
#define D_  128
#define BS_ 8192          // B*S rows
#define PD_ (P_*D_)       // 16384 floats = 64 KB
#define NB_ 256           // privatized partial tables (= K1 grid)

// Kernel 1: per-block partial means tables in LDS -> ws (non-atomic writeout).
// 512 threads = 8 waves; each wave owns rows rbase + 8*j, j=0..3, fully
// prefetched (16 outstanding global loads, fits in registers) so the 4
// shuffle->LDS-atomic chains overlap instead of serializing.
// 256 blocks x 64KB LDS -> 2 blocks/CU across all 256 CUs.
__global__ __launch_bounds__(512) void scatter_partials(
    const int* __restrict__ idx, const float* __restrict__ keys,
    const float* __restrict__ values, float* __restrict__ partials)
{
    __shared__ float lmeans[PD_];
    float4* lm4 = (float4*)lmeans;
    const int tid = threadIdx.x;
    for (int i = tid; i < PD_ / 4; i += 512) lm4[i] = float4{0.f, 0.f, 0.f, 0.f};
    __syncthreads();

    const int lane = tid & 63;
    const int wave = tid >> 6;                 // 0..7
    const int rbase = blockIdx.x * 32 + wave;  // rows: rbase + 8*j

    float kv[4], va[4], vb[4];
    int2  ii[4];
    #pragma unroll
    for (int j = 0; j < 4; ++j) {
        const int r = rbase + 8 * j;
        kv[j] = keys[(size_t)r * 64 + lane];          // [K=2,C=32] flat
        ii[j] = ((const int2*)idx)[r];                // both partition ids
        va[j] = values[(size_t)r * D_ + lane];
        vb[j] = values[(size_t)r * D_ + 64 + lane];
    }

    #pragma unroll
    for (int j = 0; j < 4; ++j) {
        float s = kv[j];
        s += __shfl_xor(s, 16);   // reduce within each 32-lane half
        s += __shfl_xor(s, 8);
        s += __shfl_xor(s, 4);
        s += __shfl_xor(s, 2);
        s += __shfl_xor(s, 1);
        const float ks0 = __shfl(s, 0)  * (1.f / 32.f);  // mean_c keys[r,0,:]
        const float ks1 = __shfl(s, 32) * (1.f / 32.f);  // mean_c keys[r,1,:]
        // stride-1 across lanes -> 2 lanes/bank, conflict-free
        atomicAdd(&lmeans[ii[j].x * D_ + lane],      ks0 * va[j]);
        atomicAdd(&lmeans[ii[j].x * D_ + 64 + lane], ks0 * vb[j]);
        atomicAdd(&lmeans[ii[j].y * D_ + lane],      ks1 * va[j]);
        atomicAdd(&lmeans[ii[j].y * D_ + 64 + lane], ks1 * vb[j]);
    }
    __syncthreads();

    float4* dst = (float4*)(partials + (size_t)blockIdx.x * PD_);
    for (int i = tid; i < PD_ / 4; i += 512) dst[i] = lm4[i];
}

// Kernel 2: means[e] = sum_b partials[b][e]. 256 blocks x 256 threads;
// block owns 64 elements, the 4 waves split the b-range (64 tables each),
// cross-wave combine through LDS. Every CU gets a block.
__global__ __launch_bounds__(256) void reduce_partials(
    const float* __restrict__ partials, float* __restrict__ means)
{
    __shared__ float red[4][64];
    const int t  = threadIdx.x;
    const int el = t & 63;                  // element within block's chunk
    const int g  = t >> 6;                  // b-group 0..3
    const int e  = blockIdx.x * 64 + el;    // global element 0..16383
    float s = 0.f;
    #pragma unroll 8
    for (int j = 0; j < 64; ++j)
        s += partials[(size_t)(g * 64 + j) * PD_ + e];
    red[g][el] = s;
    __syncthreads();
    if (t < 64)
        means[blockIdx.x * 64 + t] = red[0][t] + red[1][t] + red[2][t] + red[3][t];
}

// Kernel 3: thread-per-float4. gid covers BS_*D_/4 = 262144 float4s.
// 32 consecutive lanes share one row -> means gathers are 512B segments.
__global__ __launch_bounds__(256) void emit_out(
    const int* __restrict__ idx, const float* __restrict__ means,
    const float* __restrict__ queries, float* __restrict__ out)
{
    const int gid = blockIdx.x * 256 + threadIdx.x;   // [0, 262144)
    const int row = gid >> 5;                          // 32 float4 per row
    const int d4  = gid & 31;
    const int2 ii = ((const int2*)idx)[row];
    const float4 q = ((const float4*)queries)[gid];
    const float4* m4 = (const float4*)means;
    const float4 a = m4[ii.x * 32 + d4];
    const float4 b = m4[ii.y * 32 + d4];
    float4 o;
    o.x = (a.x + b.x) * q.x;
    o.y = (a.y + b.y) * q.y;
    o.z = (a.z + b.z) * q.z;
    o.w = (a.w + b.w) * q.w;
    ((float4*)out)[gid] = o;
}

extern "C" void kernel_launch(void* const* d_in, const int* in_sizes, int n_in,
                              void* d_out, int out_size, void* d_ws, size_t ws_size,
                              hipStream_t stream) {
    const int*   idx     = (const int*)d_in[0];    // [B,S,K] int32
    const float* keys    = (const float*)d_in[1];  // [B,S,K,C] fp32
    const float* values  = (const float*)d_in[2];  // [B,S,D]  fp32
    const float* queries = (const float*)d_in[3];  // [B,S,D]  fp32
    float* out = (float*)d_out;
    float* ws  = (float*)d_ws;

    // ws layout: [NB_ partial tables of PD_ floats][1 final means table]
    float* partials = ws;
    float* means    = ws + (size_t)NB_ * PD_;

    scatter_partials<<<NB_, 512, 0, stream>>>(idx, keys, values, partials);
    reduce_partials<<<PD_ / 64, 256, 0, stream>>>(partials, means);
    emit_out<<<(BS_ * D_ / 4) / 256, 256, 0, stream>>>(idx, means, queries, out);
}